// Round 1
// baseline (6399.441 us; speedup 1.0000x reference)
//
#include <hip/hip_runtime.h>
#include <stdint.h>

#define Nn 65536
#define Ee 131072
#define Dd 512
#define D2 1024
#define Ll 5
#define Gg 512
#define EPSf 1e-5f

typedef __bf16 bf16x8 __attribute__((ext_vector_type(8)));
typedef float f32x4 __attribute__((ext_vector_type(4)));
typedef unsigned short u16x8 __attribute__((ext_vector_type(8)));

__device__ __forceinline__ unsigned short f2bf(float f) {
    union { float f; unsigned u; } c; c.f = f;
    unsigned r = c.u + 0x7fffu + ((c.u >> 16) & 1u);
    return (unsigned short)(r >> 16);
}

__device__ __forceinline__ void gload_lds16(const void* g, void* l) {
    __builtin_amdgcn_global_load_lds(
        (const __attribute__((address_space(1))) void*)(uintptr_t)g,
        (__attribute__((address_space(3))) void*)(unsigned)(uintptr_t)l,
        16, 0, 0);
}

// ---------------- weight transpose: src [L][K][Nw] f32 -> dst [L][Nw][K] bf16
__global__ void k_transW(const float* __restrict__ src, unsigned short* __restrict__ dst,
                         int K, int Nw) {
    long total = (long)Ll * K * Nw;
    for (long idx = (long)blockIdx.x * blockDim.x + threadIdx.x; idx < total;
         idx += (long)gridDim.x * blockDim.x) {
        long l = idx / ((long)K * Nw);
        long rem = idx - l * (long)K * Nw;
        int k = (int)(rem / Nw), n = (int)(rem % Nw);
        dst[(l * Nw + n) * K + k] = f2bf(src[idx]);
    }
}

// ---------------- atom embedding + layer-0 agg init (self loop)
__global__ void k_embed(const int* __restrict__ x,
                        const float4* __restrict__ xe1, const float4* __restrict__ xe2,
                        const float4* __restrict__ es1, const float4* __restrict__ es2,
                        float4* __restrict__ h4, float4* __restrict__ agg4) {
    const int total = Nn * 128;
    for (int idx = blockIdx.x * blockDim.x + threadIdx.x; idx < total;
         idx += gridDim.x * blockDim.x) {
        int node = idx >> 7, c = idx & 127;
        int t0 = x[2 * node], t1 = x[2 * node + 1];
        float4 v = xe1[t0 * 128 + c];
        float4 w = xe2[t1 * 128 + c];
        v.x += w.x; v.y += w.y; v.z += w.z; v.w += w.w;
        h4[idx] = v;
        float4 a = es1[c], b = es2[c];
        float4 o; o.x = v.x + a.x + b.x; o.y = v.y + a.y + b.y;
        o.z = v.z + a.z + b.z; o.w = v.w + a.w + b.w;
        agg4[idx] = o;
    }
}

// ---------------- edge scatter: agg[dst] += h[src] + e1[a0] + e2[a1]
__global__ void k_scatter(const float* __restrict__ h,
                          const int* __restrict__ esrc, const int* __restrict__ edst,
                          const int* __restrict__ eattr,
                          const float* __restrict__ e1, const float* __restrict__ e2,
                          float* __restrict__ agg) {
    int e = (blockIdx.x << 2) + (threadIdx.x >> 6);
    if (e >= Ee) return;
    int lane = threadIdx.x & 63;
    int s = esrc[e], dd = edst[e];
    int a0 = eattr[2 * e], a1 = eattr[2 * e + 1];
    const float4* hs = (const float4*)(h + (size_t)s * Dd);
    const float4* p1 = (const float4*)(e1 + (size_t)a0 * Dd);
    const float4* p2 = (const float4*)(e2 + (size_t)a1 * Dd);
    float* ag = agg + (size_t)dd * Dd;
#pragma unroll
    for (int j = 0; j < 2; ++j) {
        int i4 = lane + j * 64;
        float4 v = hs[i4], q1 = p1[i4], q2 = p2[i4];
        int d = i4 * 4;
        atomicAdd(ag + d + 0, v.x + q1.x + q2.x);
        atomicAdd(ag + d + 1, v.y + q1.y + q2.y);
        atomicAdd(ag + d + 2, v.z + q1.z + q2.z);
        atomicAdd(ag + d + 3, v.w + q1.w + q2.w);
    }
}

// ---------------- f32 -> bf16 convert (8 elems / thread)
__global__ void k_tobf16(const float* __restrict__ src, unsigned short* __restrict__ dst) {
    const long total8 = (long)Nn * Dd / 8;
    for (long i = (long)blockIdx.x * blockDim.x + threadIdx.x; i < total8;
         i += (long)gridDim.x * blockDim.x) {
        const float4* s4 = (const float4*)(src + i * 8);
        float4 a = s4[0], b = s4[1];
        u16x8 o;
        o[0] = f2bf(a.x); o[1] = f2bf(a.y); o[2] = f2bf(a.z); o[3] = f2bf(a.w);
        o[4] = f2bf(b.x); o[5] = f2bf(b.y); o[6] = f2bf(b.z); o[7] = f2bf(b.w);
        *(u16x8*)(dst + i * 8) = o;
    }
}

// ---------------- bf16 GEMM, B pre-transposed: C[M,N] = A[M,K] * BT[N,K]^T + bias
// EPI 0: relu -> bf16 out ; EPI 1: f32 out
template <int EPI>
__global__ __launch_bounds__(256) void gemm_bt(const unsigned short* __restrict__ A,
                                               const unsigned short* __restrict__ BT,
                                               const float* __restrict__ bias,
                                               unsigned short* __restrict__ Cb,
                                               float* __restrict__ Cf,
                                               int M, int N, int K) {
    __shared__ __align__(16) unsigned short ldsA[128 * 32];
    __shared__ __align__(16) unsigned short ldsB[128 * 32];
    const int tid = threadIdx.x;
    const int wave = tid >> 6, lane = tid & 63;
    const int wr = wave >> 1, wc = wave & 1;
    const int l15 = lane & 15, l4 = lane >> 4;
    const long bm = (long)blockIdx.x * 128;
    const long bn = (long)blockIdx.y * 128;

    const unsigned short* ga[2];
    const unsigned short* gb[2];
    void* la[2];
    void* lb[2];
#pragma unroll
    for (int i = 0; i < 2; ++i) {
        int c = tid + i * 256;
        int r = c >> 2, kb = (c & 3) << 3;
        ga[i] = A + (bm + r) * (long)K + kb;
        gb[i] = BT + (bn + r) * (long)K + kb;
        la[i] = (char*)ldsA + (size_t)(wave * 64 + i * 256) * 16;
        lb[i] = (char*)ldsB + (size_t)(wave * 64 + i * 256) * 16;
    }

    const f32x4 zero4 = {0.f, 0.f, 0.f, 0.f};
    f32x4 acc[4][4];
#pragma unroll
    for (int m = 0; m < 4; ++m)
#pragma unroll
        for (int n = 0; n < 4; ++n) acc[m][n] = zero4;

    for (int kk = 0; kk < K; kk += 32) {
        __syncthreads();
#pragma unroll
        for (int i = 0; i < 2; ++i) {
            gload_lds16(ga[i] + kk, la[i]);
            gload_lds16(gb[i] + kk, lb[i]);
        }
        __syncthreads();
        bf16x8 af[4], bv[4];
#pragma unroll
        for (int m = 0; m < 4; ++m)
            af[m] = *(const bf16x8*)&ldsA[(wr * 64 + m * 16 + l15) * 32 + l4 * 8];
#pragma unroll
        for (int n = 0; n < 4; ++n)
            bv[n] = *(const bf16x8*)&ldsB[(wc * 64 + n * 16 + l15) * 32 + l4 * 8];
#pragma unroll
        for (int m = 0; m < 4; ++m)
#pragma unroll
            for (int n = 0; n < 4; ++n)
                acc[m][n] = __builtin_amdgcn_mfma_f32_16x16x32_bf16(af[m], bv[n], acc[m][n], 0, 0, 0);
    }

#pragma unroll
    for (int n = 0; n < 4; ++n) {
        int col = (int)bn + wc * 64 + n * 16 + l15;
        float bval = bias[col];
#pragma unroll
        for (int m = 0; m < 4; ++m) {
            long row0 = bm + wr * 64 + m * 16 + l4 * 4;
#pragma unroll
            for (int r = 0; r < 4; ++r) {
                float v = acc[m][n][r] + bval;
                if (EPI == 0) {
                    v = fmaxf(v, 0.f);
                    Cb[(row0 + r) * N + col] = f2bf(v);
                } else {
                    Cf[(row0 + r) * N + col] = v;
                }
            }
        }
    }
}

// ---------------- BN statistics
__global__ void k_zero(float* __restrict__ p) { p[threadIdx.x] = 0.f; }

__global__ void k_stats(const float* __restrict__ hh, float* __restrict__ stats) {
    int t = threadIdx.x;  // 256 threads; cols t and t+256
    long r0 = (long)blockIdx.x * 128;
    float s0 = 0.f, s1 = 0.f, q0 = 0.f, q1 = 0.f;
    for (int r = 0; r < 128; ++r) {
        const float* row = hh + (r0 + r) * Dd;
        float v0 = row[t], v1 = row[t + 256];
        s0 += v0; q0 += v0 * v0;
        s1 += v1; q1 += v1 * v1;
    }
    atomicAdd(&stats[t], s0);
    atomicAdd(&stats[t + 256], s1);
    atomicAdd(&stats[512 + t], q0);
    atomicAdd(&stats[512 + t + 256], q1);
}

__global__ void k_bnfin(const float* __restrict__ stats, const float* __restrict__ gamma,
                        const float* __restrict__ beta, float* __restrict__ ss) {
    int c = threadIdx.x;  // 512
    float mean = stats[c] * (1.f / (float)Nn);
    float var = stats[512 + c] * (1.f / (float)Nn) - mean * mean;
    float a = gamma[c] * rsqrtf(var + EPSf);
    ss[c] = a;
    ss[512 + c] = beta[c] - mean * a;
}

// ---------------- BN normalize (+relu) -> h ; optionally fused next-layer agg init
__global__ void k_norm(const float4* __restrict__ hh4, const float* __restrict__ ss,
                       float4* __restrict__ h4, float4* __restrict__ agg4,
                       const float4* __restrict__ es1, const float4* __restrict__ es2,
                       int relu) {
    const int total = Nn * 128;
    const float4* ss4 = (const float4*)ss;
    for (int idx = blockIdx.x * blockDim.x + threadIdx.x; idx < total;
         idx += gridDim.x * blockDim.x) {
        int c = idx & 127;
        float4 v = hh4[idx];
        float4 a = ss4[c], b = ss4[128 + c];
        v.x = fmaf(v.x, a.x, b.x); v.y = fmaf(v.y, a.y, b.y);
        v.z = fmaf(v.z, a.z, b.z); v.w = fmaf(v.w, a.w, b.w);
        if (relu) {
            v.x = fmaxf(v.x, 0.f); v.y = fmaxf(v.y, 0.f);
            v.z = fmaxf(v.z, 0.f); v.w = fmaxf(v.w, 0.f);
        }
        h4[idx] = v;
        if (agg4 != nullptr) {
            float4 p = es1[c], q = es2[c];
            float4 o;
            o.x = v.x + p.x + q.x; o.y = v.y + p.y + q.y;
            o.z = v.z + p.z + q.z; o.w = v.w + p.w + q.w;
            agg4[idx] = o;
        }
    }
}

// ---------------- graph mean pool (batch is sorted)
__global__ void k_pool(const float* __restrict__ h, const int* __restrict__ batch,
                       float* __restrict__ graph) {
    int g = blockIdx.x, t = threadIdx.x;  // 512 blocks, 256 threads
    int lo = 0, hi = Nn;
    while (lo < hi) { int m = (lo + hi) >> 1; if (batch[m] < g) lo = m + 1; else hi = m; }
    int s = lo;
    lo = s; hi = Nn;
    while (lo < hi) { int m = (lo + hi) >> 1; if (batch[m] <= g) lo = m + 1; else hi = m; }
    int e = lo;
    float s0 = 0.f, s1 = 0.f;
    for (int r = s; r < e; ++r) {
        const float* row = h + (long)r * Dd;
        s0 += row[t];
        s1 += row[t + 256];
    }
    int cnt = e - s; if (cnt < 1) cnt = 1;
    float inv = 1.f / (float)cnt;
    graph[(long)g * Dd + t] = s0 * inv;
    graph[(long)g * Dd + t + 256] = s1 * inv;
}

extern "C" void kernel_launch(void* const* d_in, const int* in_sizes, int n_in,
                              void* d_out, int out_size, void* d_ws, size_t ws_size,
                              hipStream_t stream) {
    (void)in_sizes; (void)n_in; (void)out_size; (void)ws_size;
    const int* x      = (const int*)d_in[0];
    const int* ei     = (const int*)d_in[1];
    const int* ea     = (const int*)d_in[2];
    const int* batch  = (const int*)d_in[3];
    const float* xe1  = (const float*)d_in[4];
    const float* xe2  = (const float*)d_in[5];
    const float* ee1  = (const float*)d_in[6];
    const float* ee2  = (const float*)d_in[7];
    const float* W1   = (const float*)d_in[8];
    const float* b1   = (const float*)d_in[9];
    const float* W2   = (const float*)d_in[10];
    const float* b2   = (const float*)d_in[11];
    const float* gamma = (const float*)d_in[12];
    const float* beta  = (const float*)d_in[13];

    float* graph = (float*)d_out;
    float* h = graph + (size_t)Gg * Dd;  // N*D f32; aliased as hh1 bf16 [N][2D]

    char* w = (char*)d_ws;
    float* bufT = (float*)w;                    w += (size_t)Nn * Dd * 4;   // agg / hh
    unsigned short* aggb = (unsigned short*)w;  w += (size_t)Nn * Dd * 2;   // agg bf16
    unsigned short* w1t = (unsigned short*)w;   w += (size_t)Ll * D2 * Dd * 2;
    unsigned short* w2t = (unsigned short*)w;   w += (size_t)Ll * Dd * D2 * 2;
    float* stats = (float*)w;                   w += 4096;
    float* ss = (float*)w;

    // weights -> bf16 transposed [N][K]
    k_transW<<<2048, 256, 0, stream>>>(W1, w1t, Dd, D2);
    k_transW<<<2048, 256, 0, stream>>>(W2, w2t, D2, Dd);

    // embedding + layer-0 agg init (self loop attr [4,0])
    k_embed<<<2048, 256, 0, stream>>>(x, (const float4*)xe1, (const float4*)xe2,
                                      (const float4*)(ee1 + 4 * Dd), (const float4*)ee2,
                                      (float4*)h, (float4*)bufT);

    for (int l = 0; l < Ll; ++l) {
        k_scatter<<<Ee / 4, 256, 0, stream>>>(h, ei, ei + Ee, ea,
                                              ee1 + (size_t)l * 6 * Dd,
                                              ee2 + (size_t)l * 3 * Dd, bufT);
        k_tobf16<<<2048, 256, 0, stream>>>(bufT, aggb);
        gemm_bt<0><<<dim3(Nn / 128, D2 / 128), 256, 0, stream>>>(
            aggb, w1t + (size_t)l * D2 * Dd, b1 + (size_t)l * D2,
            (unsigned short*)h, nullptr, Nn, D2, Dd);
        gemm_bt<1><<<dim3(Nn / 128, Dd / 128), 256, 0, stream>>>(
            (const unsigned short*)h, w2t + (size_t)l * Dd * D2, b2 + (size_t)l * Dd,
            nullptr, bufT, Nn, Dd, D2);
        k_zero<<<1, 1024, 0, stream>>>(stats);
        k_stats<<<512, 256, 0, stream>>>(bufT, stats);
        k_bnfin<<<1, 512, 0, stream>>>(stats, gamma + (size_t)l * Dd, beta + (size_t)l * Dd, ss);
        int last = (l == Ll - 1);
        int ln = last ? l : (l + 1);
        k_norm<<<2048, 256, 0, stream>>>((const float4*)bufT, ss, (float4*)h,
                                         last ? nullptr : (float4*)bufT,
                                         (const float4*)(ee1 + (size_t)(ln * 6 + 4) * Dd),
                                         (const float4*)(ee2 + (size_t)(ln * 3) * Dd),
                                         last ? 0 : 1);
    }

    k_pool<<<Gg, 256, 0, stream>>>(h, batch, graph);
}

// Round 2
// 2125.813 us; speedup vs baseline: 3.0104x; 3.0104x over previous
//
#include <hip/hip_runtime.h>
#include <stdint.h>

#define Nn 65536
#define Ee 131072
#define Dd 512
#define D2 1024
#define Ll 5
#define Gg 512
#define EPSf 1e-5f

typedef __bf16 bf16x8 __attribute__((ext_vector_type(8)));
typedef float f32x4 __attribute__((ext_vector_type(4)));

__device__ __forceinline__ unsigned short f2bf(float f) {
    union { float f; unsigned u; } c; c.f = f;
    unsigned r = c.u + 0x7fffu + ((c.u >> 16) & 1u);
    return (unsigned short)(r >> 16);
}

__device__ __forceinline__ void add4(float4& a, float4 b) {
    a.x += b.x; a.y += b.y; a.z += b.z; a.w += b.w;
}

__device__ __forceinline__ void gload_lds16(const void* g, void* l) {
    __builtin_amdgcn_global_load_lds(
        (const __attribute__((address_space(1))) void*)(uintptr_t)g,
        (__attribute__((address_space(3))) void*)(unsigned)(uintptr_t)l,
        16, 0, 0);
}

// ---------------- weight transpose: src [L][K][Nw] f32 -> dst [L][Nw][K] bf16
__global__ void k_transW(const float* __restrict__ src, unsigned short* __restrict__ dst,
                         int K, int Nw) {
    long total = (long)Ll * K * Nw;
    for (long idx = (long)blockIdx.x * blockDim.x + threadIdx.x; idx < total;
         idx += (long)gridDim.x * blockDim.x) {
        long l = idx / ((long)K * Nw);
        long rem = idx - l * (long)K * Nw;
        int k = (int)(rem / Nw), n = (int)(rem % Nw);
        dst[(l * Nw + n) * K + k] = f2bf(src[idx]);
    }
}

// ---------------- atom embedding
__global__ void k_embed(const int* __restrict__ x,
                        const float4* __restrict__ xe1, const float4* __restrict__ xe2,
                        float4* __restrict__ h4) {
    const int total = Nn * 128;
    for (int idx = blockIdx.x * blockDim.x + threadIdx.x; idx < total;
         idx += gridDim.x * blockDim.x) {
        int node = idx >> 7, c = idx & 127;
        int t0 = x[2 * node], t1 = x[2 * node + 1];
        float4 v = xe1[t0 * 128 + c];
        float4 w = xe2[t1 * 128 + c];
        v.x += w.x; v.y += w.y; v.z += w.z; v.w += w.w;
        h4[idx] = v;
    }
}

// ---------------- CSR build (dst-sorted), once per launch
__global__ void k_zeroN(int* __restrict__ p, int n) {
    int i = blockIdx.x * blockDim.x + threadIdx.x;
    if (i < n) p[i] = 0;
}

__global__ void k_hist(const int* __restrict__ edst, int* __restrict__ cnt) {
    int e = blockIdx.x * blockDim.x + threadIdx.x;
    if (e < Ee) atomicAdd(&cnt[edst[e]], 1);
}

__global__ void k_scan(const int* __restrict__ cnt, int* __restrict__ off,
                       int* __restrict__ cursor) {
    __shared__ int part[1024];
    int t = threadIdx.x;
    int base = t * 64;
    int s = 0;
    for (int i = 0; i < 64; ++i) s += cnt[base + i];
    part[t] = s;
    __syncthreads();
    for (int d = 1; d < 1024; d <<= 1) {
        int v = (t >= d) ? part[t - d] : 0;
        __syncthreads();
        part[t] += v;
        __syncthreads();
    }
    int run = part[t] - s;  // exclusive prefix
    for (int i = 0; i < 64; ++i) {
        off[base + i] = run;
        cursor[base + i] = run;
        run += cnt[base + i];
    }
    if (t == 1023) off[Nn] = run;
}

__global__ void k_place(const int* __restrict__ esrc, const int* __restrict__ edst,
                        const int* __restrict__ eattr, int* __restrict__ cursor,
                        int* __restrict__ csrc, int* __restrict__ cattr) {
    int e = blockIdx.x * blockDim.x + threadIdx.x;
    if (e < Ee) {
        int d = edst[e];
        int p = atomicAdd(&cursor[d], 1);
        csrc[p] = esrc[e];
        cattr[p] = eattr[2 * e] * 3 + eattr[2 * e + 1];
    }
}

// ---------------- gather: agg[n] = h[n]+sl + sum_{e in(n)} (h[src]+e1[a0]+e2[a1]) -> bf16
__global__ __launch_bounds__(256) void k_gather(const float* __restrict__ h,
                                                const int* __restrict__ off,
                                                const int* __restrict__ csrc,
                                                const int* __restrict__ cattr,
                                                const float* __restrict__ e1l,
                                                const float* __restrict__ e2l,
                                                unsigned short* __restrict__ aggb) {
    int node = (blockIdx.x << 2) + (threadIdx.x >> 6);
    int lane = threadIdx.x & 63;
    int c0 = lane, c1 = lane + 64;
    const float4* hn = (const float4*)(h + (size_t)node * Dd);
    const float4* s1 = (const float4*)(e1l + 4 * Dd);  // self-loop attr [4,0]
    const float4* s2 = (const float4*)(e2l);
    float4 A0 = hn[c0], A1 = hn[c1];
    add4(A0, s1[c0]); add4(A0, s2[c0]);
    add4(A1, s1[c1]); add4(A1, s2[c1]);
    int kb = off[node], ke = off[node + 1];
    for (int k = kb; k < ke; ++k) {
        int s = csrc[k];
        int at = cattr[k];
        const float4* hs = (const float4*)(h + (size_t)s * Dd);
        const float4* p1 = (const float4*)(e1l + (size_t)(at / 3) * Dd);
        const float4* p2 = (const float4*)(e2l + (size_t)(at % 3) * Dd);
        add4(A0, hs[c0]); add4(A0, p1[c0]); add4(A0, p2[c0]);
        add4(A1, hs[c1]); add4(A1, p1[c1]); add4(A1, p2[c1]);
    }
    unsigned short* dst = aggb + (size_t)node * Dd;
    ushort4 o0, o1;
    o0.x = f2bf(A0.x); o0.y = f2bf(A0.y); o0.z = f2bf(A0.z); o0.w = f2bf(A0.w);
    o1.x = f2bf(A1.x); o1.y = f2bf(A1.y); o1.z = f2bf(A1.z); o1.w = f2bf(A1.w);
    *(ushort4*)(dst + c0 * 4) = o0;
    *(ushort4*)(dst + c1 * 4) = o1;
}

// ---------------- bf16 GEMM, B pre-transposed: C[M,N] = A[M,K] * BT[N,K]^T + bias
// EPI 0: relu -> bf16 out ; EPI 1: f32 out + fused BN column stats (atomics)
template <int EPI>
__global__ __launch_bounds__(256) void gemm_bt(const unsigned short* __restrict__ A,
                                               const unsigned short* __restrict__ BT,
                                               const float* __restrict__ bias,
                                               unsigned short* __restrict__ Cb,
                                               float* __restrict__ Cf,
                                               float* __restrict__ stats,
                                               int M, int N, int K) {
    __shared__ __align__(16) unsigned short ldsA[128 * 32];
    __shared__ __align__(16) unsigned short ldsB[128 * 32];
    const int tid = threadIdx.x;
    const int wave = tid >> 6, lane = tid & 63;
    const int wr = wave >> 1, wc = wave & 1;
    const int l15 = lane & 15, l4 = lane >> 4;
    const long bm = (long)blockIdx.x * 128;
    const long bn = (long)blockIdx.y * 128;

    const unsigned short* ga[2];
    const unsigned short* gb[2];
    void* la[2];
    void* lb[2];
#pragma unroll
    for (int i = 0; i < 2; ++i) {
        int c = tid + i * 256;
        int r = c >> 2, kb = (c & 3) << 3;
        ga[i] = A + (bm + r) * (long)K + kb;
        gb[i] = BT + (bn + r) * (long)K + kb;
        la[i] = (char*)ldsA + (size_t)(wave * 64 + i * 256) * 16;
        lb[i] = (char*)ldsB + (size_t)(wave * 64 + i * 256) * 16;
    }

    const f32x4 zero4 = {0.f, 0.f, 0.f, 0.f};
    f32x4 acc[4][4];
#pragma unroll
    for (int m = 0; m < 4; ++m)
#pragma unroll
        for (int n = 0; n < 4; ++n) acc[m][n] = zero4;

    for (int kk = 0; kk < K; kk += 32) {
        __syncthreads();
#pragma unroll
        for (int i = 0; i < 2; ++i) {
            gload_lds16(ga[i] + kk, la[i]);
            gload_lds16(gb[i] + kk, lb[i]);
        }
        __syncthreads();
        bf16x8 af[4], bv[4];
#pragma unroll
        for (int m = 0; m < 4; ++m)
            af[m] = *(const bf16x8*)&ldsA[(wr * 64 + m * 16 + l15) * 32 + l4 * 8];
#pragma unroll
        for (int n = 0; n < 4; ++n)
            bv[n] = *(const bf16x8*)&ldsB[(wc * 64 + n * 16 + l15) * 32 + l4 * 8];
#pragma unroll
        for (int m = 0; m < 4; ++m)
#pragma unroll
            for (int n = 0; n < 4; ++n)
                acc[m][n] = __builtin_amdgcn_mfma_f32_16x16x32_bf16(af[m], bv[n], acc[m][n], 0, 0, 0);
    }

    float cs[4] = {0.f, 0.f, 0.f, 0.f}, cq[4] = {0.f, 0.f, 0.f, 0.f};
#pragma unroll
    for (int n = 0; n < 4; ++n) {
        int col = (int)bn + wc * 64 + n * 16 + l15;
        float bval = bias[col];
#pragma unroll
        for (int m = 0; m < 4; ++m) {
            long row0 = bm + wr * 64 + m * 16 + l4 * 4;
#pragma unroll
            for (int r = 0; r < 4; ++r) {
                float v = acc[m][n][r] + bval;
                if (EPI == 0) {
                    v = fmaxf(v, 0.f);
                    Cb[(row0 + r) * N + col] = f2bf(v);
                } else {
                    Cf[(row0 + r) * N + col] = v;
                    cs[n] += v;
                    cq[n] += v * v;
                }
            }
        }
    }
    if (EPI == 1) {
#pragma unroll
        for (int n = 0; n < 4; ++n) {
            float s = cs[n], q = cq[n];
            s += __shfl_xor(s, 16); s += __shfl_xor(s, 32);
            q += __shfl_xor(q, 16); q += __shfl_xor(q, 32);
            if (l4 == 0) {
                int col = (int)bn + wc * 64 + n * 16 + l15;
                atomicAdd(&stats[col], s);
                atomicAdd(&stats[512 + col], q);
            }
        }
    }
}

// ---------------- BN finalize
__global__ void k_zero(float* __restrict__ p) { p[threadIdx.x] = 0.f; }

__global__ void k_bnfin(const float* __restrict__ stats, const float* __restrict__ gamma,
                        const float* __restrict__ beta, float* __restrict__ ss) {
    int c = threadIdx.x;  // 512
    float mean = stats[c] * (1.f / (float)Nn);
    float var = stats[512 + c] * (1.f / (float)Nn) - mean * mean;
    float a = gamma[c] * rsqrtf(var + EPSf);
    ss[c] = a;
    ss[512 + c] = beta[c] - mean * a;
}

// ---------------- BN normalize (+relu) -> h f32
__global__ void k_norm(const float4* __restrict__ hh4, const float* __restrict__ ss,
                       float4* __restrict__ h4, int relu) {
    const int total = Nn * 128;
    const float4* ss4 = (const float4*)ss;
    for (int idx = blockIdx.x * blockDim.x + threadIdx.x; idx < total;
         idx += gridDim.x * blockDim.x) {
        int c = idx & 127;
        float4 v = hh4[idx];
        float4 a = ss4[c], b = ss4[128 + c];
        v.x = fmaf(v.x, a.x, b.x); v.y = fmaf(v.y, a.y, b.y);
        v.z = fmaf(v.z, a.z, b.z); v.w = fmaf(v.w, a.w, b.w);
        if (relu) {
            v.x = fmaxf(v.x, 0.f); v.y = fmaxf(v.y, 0.f);
            v.z = fmaxf(v.z, 0.f); v.w = fmaxf(v.w, 0.f);
        }
        h4[idx] = v;
    }
}

// ---------------- graph mean pool (batch is sorted)
__global__ void k_pool(const float* __restrict__ h, const int* __restrict__ batch,
                       float* __restrict__ graph) {
    int g = blockIdx.x, t = threadIdx.x;  // 512 blocks, 256 threads
    int lo = 0, hi = Nn;
    while (lo < hi) { int m = (lo + hi) >> 1; if (batch[m] < g) lo = m + 1; else hi = m; }
    int s = lo;
    lo = s; hi = Nn;
    while (lo < hi) { int m = (lo + hi) >> 1; if (batch[m] <= g) lo = m + 1; else hi = m; }
    int e = lo;
    float s0 = 0.f, s1 = 0.f;
    for (int r = s; r < e; ++r) {
        const float* row = h + (long)r * Dd;
        s0 += row[t];
        s1 += row[t + 256];
    }
    int cnt = e - s; if (cnt < 1) cnt = 1;
    float inv = 1.f / (float)cnt;
    graph[(long)g * Dd + t] = s0 * inv;
    graph[(long)g * Dd + t + 256] = s1 * inv;
}

extern "C" void kernel_launch(void* const* d_in, const int* in_sizes, int n_in,
                              void* d_out, int out_size, void* d_ws, size_t ws_size,
                              hipStream_t stream) {
    (void)in_sizes; (void)n_in; (void)out_size; (void)ws_size;
    const int* x      = (const int*)d_in[0];
    const int* ei     = (const int*)d_in[1];
    const int* ea     = (const int*)d_in[2];
    const int* batch  = (const int*)d_in[3];
    const float* xe1  = (const float*)d_in[4];
    const float* xe2  = (const float*)d_in[5];
    const float* ee1  = (const float*)d_in[6];
    const float* ee2  = (const float*)d_in[7];
    const float* W1   = (const float*)d_in[8];
    const float* b1   = (const float*)d_in[9];
    const float* W2   = (const float*)d_in[10];
    const float* b2   = (const float*)d_in[11];
    const float* gamma = (const float*)d_in[12];
    const float* beta  = (const float*)d_in[13];

    float* graph = (float*)d_out;
    float* h = graph + (size_t)Gg * Dd;  // N*D f32; aliased as hh1 bf16 [N][2D]

    char* w = (char*)d_ws;
    float* bufT = (float*)w;                    w += (size_t)Nn * Dd * 4;   // hh (GEMM2 out, f32)
    unsigned short* aggb = (unsigned short*)w;  w += (size_t)Nn * Dd * 2;   // agg bf16
    unsigned short* w1t = (unsigned short*)w;   w += (size_t)Ll * D2 * Dd * 2;
    unsigned short* w2t = (unsigned short*)w;   w += (size_t)Ll * Dd * D2 * 2;
    float* stats = (float*)w;                   w += 4096;
    float* ss = (float*)w;                      w += 4096;
    int* csr_off = (int*)w;                     w += (Nn + 1) * 4;
    int* cursor = (int*)w;                      w += Nn * 4;
    int* cnt = (int*)w;                         w += Nn * 4;
    int* csrc = (int*)w;                        w += Ee * 4;
    int* cattr = (int*)w;                       w += Ee * 4;

    // weights -> bf16 transposed [N][K]
    k_transW<<<2048, 256, 0, stream>>>(W1, w1t, Dd, D2);
    k_transW<<<2048, 256, 0, stream>>>(W2, w2t, D2, Dd);

    // atom embedding
    k_embed<<<2048, 256, 0, stream>>>(x, (const float4*)xe1, (const float4*)xe2, (float4*)h);

    // CSR build (topology constant across layers)
    k_zeroN<<<64, 1024, 0, stream>>>(cnt, Nn);
    k_hist<<<Ee / 256, 256, 0, stream>>>(ei + Ee, cnt);
    k_scan<<<1, 1024, 0, stream>>>(cnt, csr_off, cursor);
    k_place<<<Ee / 256, 256, 0, stream>>>(ei, ei + Ee, ea, cursor, csrc, cattr);

    for (int l = 0; l < Ll; ++l) {
        const float* e1l = ee1 + (size_t)l * 6 * Dd;
        const float* e2l = ee2 + (size_t)l * 3 * Dd;
        k_gather<<<Nn / 4, 256, 0, stream>>>(h, csr_off, csrc, cattr, e1l, e2l, aggb);
        gemm_bt<0><<<dim3(Nn / 128, D2 / 128), 256, 0, stream>>>(
            aggb, w1t + (size_t)l * D2 * Dd, b1 + (size_t)l * D2,
            (unsigned short*)h, nullptr, nullptr, Nn, D2, Dd);
        k_zero<<<1, 1024, 0, stream>>>(stats);
        gemm_bt<1><<<dim3(Nn / 128, Dd / 128), 256, 0, stream>>>(
            (const unsigned short*)h, w2t + (size_t)l * Dd * D2, b2 + (size_t)l * Dd,
            nullptr, bufT, stats, Nn, Dd, D2);
        k_bnfin<<<1, 512, 0, stream>>>(stats, gamma + (size_t)l * Dd, beta + (size_t)l * Dd, ss);
        k_norm<<<2048, 256, 0, stream>>>((const float4*)bufT, ss, (float4*)h, l != Ll - 1);
    }

    k_pool<<<Gg, 256, 0, stream>>>(h, batch, graph);
}

// Round 3
// 1631.388 us; speedup vs baseline: 3.9227x; 1.3031x over previous
//
#include <hip/hip_runtime.h>
#include <stdint.h>

#define Nn 65536
#define Ee 131072
#define Dd 512
#define D2 1024
#define Ll 5
#define Gg 512
#define EPSf 1e-5f

typedef __bf16 bf16x8 __attribute__((ext_vector_type(8)));
typedef float f32x4 __attribute__((ext_vector_type(4)));

__device__ __forceinline__ unsigned short f2bf(float f) {
    union { float f; unsigned u; } c; c.f = f;
    unsigned r = c.u + 0x7fffu + ((c.u >> 16) & 1u);
    return (unsigned short)(r >> 16);
}

__device__ __forceinline__ void add4(float4& a, float4 b) {
    a.x += b.x; a.y += b.y; a.z += b.z; a.w += b.w;
}

__device__ __forceinline__ void gload_lds16(const void* g, void* l) {
    __builtin_amdgcn_global_load_lds(
        (const __attribute__((address_space(1))) void*)(uintptr_t)g,
        (__attribute__((address_space(3))) void*)(unsigned)(uintptr_t)l,
        16, 0, 0);
}

// ---------------- weight transpose: src [L][K][Nw] f32 -> dst [L][Nw][K] bf16
__global__ void k_transW(const float* __restrict__ src, unsigned short* __restrict__ dst,
                         int K, int Nw) {
    long total = (long)Ll * K * Nw;
    for (long idx = (long)blockIdx.x * blockDim.x + threadIdx.x; idx < total;
         idx += (long)gridDim.x * blockDim.x) {
        long l = idx / ((long)K * Nw);
        long rem = idx - l * (long)K * Nw;
        int k = (int)(rem / Nw), n = (int)(rem % Nw);
        dst[(l * Nw + n) * K + k] = f2bf(src[idx]);
    }
}

// ---------------- atom embedding
__global__ void k_embed(const int* __restrict__ x,
                        const float4* __restrict__ xe1, const float4* __restrict__ xe2,
                        float4* __restrict__ h4) {
    const int total = Nn * 128;
    for (int idx = blockIdx.x * blockDim.x + threadIdx.x; idx < total;
         idx += gridDim.x * blockDim.x) {
        int node = idx >> 7, c = idx & 127;
        int t0 = x[2 * node], t1 = x[2 * node + 1];
        float4 v = xe1[t0 * 128 + c];
        float4 w = xe2[t1 * 128 + c];
        v.x += w.x; v.y += w.y; v.z += w.z; v.w += w.w;
        h4[idx] = v;
    }
}

// ---------------- CSR build (dst-sorted), once per launch
__global__ void k_zeroN(int* __restrict__ p, int n) {
    int i = blockIdx.x * blockDim.x + threadIdx.x;
    if (i < n) p[i] = 0;
}

__global__ void k_hist(const int* __restrict__ edst, int* __restrict__ cnt) {
    int e = blockIdx.x * blockDim.x + threadIdx.x;
    if (e < Ee) atomicAdd(&cnt[edst[e]], 1);
}

__global__ void k_scan(const int* __restrict__ cnt, int* __restrict__ off,
                       int* __restrict__ cursor) {
    __shared__ int part[1024];
    int t = threadIdx.x;
    int base = t * 64;
    int s = 0;
    for (int i = 0; i < 64; ++i) s += cnt[base + i];
    part[t] = s;
    __syncthreads();
    for (int d = 1; d < 1024; d <<= 1) {
        int v = (t >= d) ? part[t - d] : 0;
        __syncthreads();
        part[t] += v;
        __syncthreads();
    }
    int run = part[t] - s;  // exclusive prefix
    for (int i = 0; i < 64; ++i) {
        off[base + i] = run;
        cursor[base + i] = run;
        run += cnt[base + i];
    }
    if (t == 1023) off[Nn] = run;
}

__global__ void k_place(const int* __restrict__ esrc, const int* __restrict__ edst,
                        const int* __restrict__ eattr, int* __restrict__ cursor,
                        int* __restrict__ csrc, int* __restrict__ cattr) {
    int e = blockIdx.x * blockDim.x + threadIdx.x;
    if (e < Ee) {
        int d = edst[e];
        int p = atomicAdd(&cursor[d], 1);
        csrc[p] = esrc[e];
        cattr[p] = eattr[2 * e] * 3 + eattr[2 * e + 1];
    }
}

// ---------------- gather (+fused BN affine+relu of the PREVIOUS layer's hh)
// NORM=0: rows read raw from hin. NORM=1: row value = relu(hin*a + b) per column.
template <int NORM>
__global__ __launch_bounds__(256) void k_gather(const float* __restrict__ hin,
                                                const float* __restrict__ ss,
                                                const int* __restrict__ off,
                                                const int* __restrict__ csrc,
                                                const int* __restrict__ cattr,
                                                const float* __restrict__ e1l,
                                                const float* __restrict__ e2l,
                                                unsigned short* __restrict__ aggb) {
    int node = (blockIdx.x << 2) + (threadIdx.x >> 6);
    int lane = threadIdx.x & 63;
    int c0 = lane, c1 = lane + 64;
    float4 sa0, sb0, sa1, sb1;
    if (NORM) {
        const float4* ss4 = (const float4*)ss;
        sa0 = ss4[c0]; sb0 = ss4[128 + c0];
        sa1 = ss4[c1]; sb1 = ss4[128 + c1];
    }
    auto loadrow = [&](const float4* row, int c, float4 a, float4 b) -> float4 {
        float4 v = row[c];
        if (NORM) {
            v.x = fmaxf(fmaf(v.x, a.x, b.x), 0.f);
            v.y = fmaxf(fmaf(v.y, a.y, b.y), 0.f);
            v.z = fmaxf(fmaf(v.z, a.z, b.z), 0.f);
            v.w = fmaxf(fmaf(v.w, a.w, b.w), 0.f);
        }
        return v;
    };
    const float4* hn = (const float4*)(hin + (size_t)node * Dd);
    const float4* s1 = (const float4*)(e1l + 4 * Dd);  // self-loop attr [4,0]
    const float4* s2 = (const float4*)(e2l);
    float4 A0 = loadrow(hn, c0, sa0, sb0);
    float4 A1 = loadrow(hn, c1, sa1, sb1);
    add4(A0, s1[c0]); add4(A0, s2[c0]);
    add4(A1, s1[c1]); add4(A1, s2[c1]);
    int kb = off[node], ke = off[node + 1];
    for (int k = kb; k < ke; ++k) {
        int s = csrc[k];
        int at = cattr[k];
        const float4* hs = (const float4*)(hin + (size_t)s * Dd);
        const float4* p1 = (const float4*)(e1l + (size_t)(at / 3) * Dd);
        const float4* p2 = (const float4*)(e2l + (size_t)(at % 3) * Dd);
        add4(A0, loadrow(hs, c0, sa0, sb0)); add4(A0, p1[c0]); add4(A0, p2[c0]);
        add4(A1, loadrow(hs, c1, sa1, sb1)); add4(A1, p1[c1]); add4(A1, p2[c1]);
    }
    unsigned short* dst = aggb + (size_t)node * Dd;
    ushort4 o0, o1;
    o0.x = f2bf(A0.x); o0.y = f2bf(A0.y); o0.z = f2bf(A0.z); o0.w = f2bf(A0.w);
    o1.x = f2bf(A1.x); o1.y = f2bf(A1.y); o1.z = f2bf(A1.z); o1.w = f2bf(A1.w);
    *(ushort4*)(dst + c0 * 4) = o0;
    *(ushort4*)(dst + c1 * 4) = o1;
}

// ================ pipelined 256x256 GEMM, BK=64, 8 waves (2M x 4N), 128KB LDS
// A [M][K] bf16, BT [N][K] bf16. EPI 0: relu->bf16 ; EPI 1: f32 + BN stats.
// LDS regions per (dbuf, khalf): [256 rows][32 cols] bf16 = 16KB, swizzled:
//   byte = row*64 + ((k16 ^ ((row>>1)&3))<<4), k16 in 0..3.
// Staged via global_load_lds (linear dest) with pre-swizzled global source.
__device__ __forceinline__ void stage_q(const unsigned short* __restrict__ g, int ldk,
                                        long row0, int col0, char* region, int tid) {
    int wbase = (tid >> 6) << 10;  // wave * 1024 bytes
#pragma unroll
    for (int r = 0; r < 2; ++r) {
        int gi = tid + r * 512;            // granule 0..1023
        int row = gi >> 2;
        int k16 = (gi & 3) ^ ((row >> 1) & 3);
        gload_lds16(g + (row0 + row) * (long)ldk + col0 + k16 * 8,
                    region + r * 8192 + wbase);
    }
}

__device__ __forceinline__ bf16x8 rd_frag(const char* region, int row, int l4) {
    int slot = l4 ^ ((row >> 1) & 3);
    return *(const bf16x8*)(region + row * 64 + (slot << 4));
}

template <int EPI>
__global__ __launch_bounds__(512, 2) void gemm8(const unsigned short* __restrict__ A,
                                                const unsigned short* __restrict__ BT,
                                                const float* __restrict__ bias,
                                                unsigned short* __restrict__ Cb,
                                                float* __restrict__ Cf,
                                                float* __restrict__ stats,
                                                int M, int N, int K) {
    __shared__ __align__(16) char lds[131072];
    const int tid = threadIdx.x;
    const int lane = tid & 63;
    const int w = tid >> 6;
    const int wm = w >> 2, wn = w & 3;
    const int l15 = lane & 15, l4 = lane >> 4;

    // XCD-aware swizzle (nwg % 8 == 0 for our shapes)
    const int nwg = gridDim.x;
    const int cpx = nwg >> 3;
    const int bid = blockIdx.x;
    const int wg = (bid & 7) * cpx + (bid >> 3);
    const int ntn = N >> 8;
    const long bm = (long)(wg / ntn) * 256;
    const long bn = (long)(wg % ntn) * 256;

    char* Ab = lds;            // [dbuf][kh][16384]
    char* Bb = lds + 65536;
    const int NT = K >> 6;

    f32x4 acc[8][4];
#pragma unroll
    for (int i = 0; i < 8; ++i)
#pragma unroll
        for (int j = 0; j < 4; ++j) acc[i][j] = (f32x4){0.f, 0.f, 0.f, 0.f};

    // ---- prologue: tile0 (4 quarters) + tile1 kh0 (A,B); leave last 4 loads in flight
    stage_q(A, K, bm, 0, Ab, tid);
    stage_q(BT, K, bn, 0, Bb, tid);
    stage_q(A, K, bm, 32, Ab + 16384, tid);
    stage_q(BT, K, bn, 32, Bb + 16384, tid);
    if (NT > 1) {
        stage_q(A, K, bm, 64, Ab + 32768, tid);
        stage_q(BT, K, bn, 64, Bb + 32768, tid);
    }
    asm volatile("s_waitcnt vmcnt(4)" ::: "memory");
    __builtin_amdgcn_s_barrier();

    for (int t = 0; t < NT; ++t) {
        const int cur = t & 1;
        char* Acur = Ab + cur * 32768;
        char* Bcur = Bb + cur * 32768;
        char* Anxt = Ab + (cur ^ 1) * 32768;
        char* Bnxt = Bb + (cur ^ 1) * 32768;
        bf16x8 af[8], bv[2];

        // ---- phase 1: ks=0, nh=0 ; stage Ak1(t+1) -> other buf kh1
#pragma unroll
        for (int fm = 0; fm < 8; ++fm)
            af[fm] = rd_frag(Acur, wm * 128 + fm * 16 + l15, l4);
#pragma unroll
        for (int fn = 0; fn < 2; ++fn)
            bv[fn] = rd_frag(Bcur, wn * 64 + fn * 16 + l15, l4);
        if (t + 1 < NT) stage_q(A, K, bm, (t + 1) * 64 + 32, Anxt + 16384, tid);
        __builtin_amdgcn_s_barrier();
        asm volatile("s_waitcnt lgkmcnt(0)" ::: "memory");
        __builtin_amdgcn_s_setprio(1);
#pragma unroll
        for (int fm = 0; fm < 8; ++fm)
#pragma unroll
            for (int fn = 0; fn < 2; ++fn)
                acc[fm][fn] = __builtin_amdgcn_mfma_f32_16x16x32_bf16(af[fm], bv[fn], acc[fm][fn], 0, 0, 0);
        __builtin_amdgcn_s_setprio(0);
        __builtin_amdgcn_s_barrier();

        // ---- phase 2: ks=0, nh=1 ; stage Bk1(t+1)
#pragma unroll
        for (int fn = 0; fn < 2; ++fn)
            bv[fn] = rd_frag(Bcur, wn * 64 + 32 + fn * 16 + l15, l4);
        if (t + 1 < NT) stage_q(BT, K, bn, (t + 1) * 64 + 32, Bnxt + 16384, tid);
        __builtin_amdgcn_s_barrier();
        asm volatile("s_waitcnt lgkmcnt(0)" ::: "memory");
        __builtin_amdgcn_s_setprio(1);
#pragma unroll
        for (int fm = 0; fm < 8; ++fm)
#pragma unroll
            for (int fn = 0; fn < 2; ++fn)
                acc[fm][2 + fn] = __builtin_amdgcn_mfma_f32_16x16x32_bf16(af[fm], bv[fn], acc[fm][2 + fn], 0, 0, 0);
        __builtin_amdgcn_s_setprio(0);
        __builtin_amdgcn_s_barrier();

        // ---- phase 3: ks=1, nh=0 ; stage Ak0(t+2) -> SAME buf kh0 (freed after p2)
#pragma unroll
        for (int fm = 0; fm < 8; ++fm)
            af[fm] = rd_frag(Acur + 16384, wm * 128 + fm * 16 + l15, l4);
#pragma unroll
        for (int fn = 0; fn < 2; ++fn)
            bv[fn] = rd_frag(Bcur + 16384, wn * 64 + fn * 16 + l15, l4);
        if (t + 2 < NT) stage_q(A, K, bm, (t + 2) * 64, Acur, tid);
        __builtin_amdgcn_s_barrier();
        asm volatile("s_waitcnt lgkmcnt(0)" ::: "memory");
        __builtin_amdgcn_s_setprio(1);
#pragma unroll
        for (int fm = 0; fm < 8; ++fm)
#pragma unroll
            for (int fn = 0; fn < 2; ++fn)
                acc[fm][fn] = __builtin_amdgcn_mfma_f32_16x16x32_bf16(af[fm], bv[fn], acc[fm][fn], 0, 0, 0);
        __builtin_amdgcn_s_setprio(0);
        __builtin_amdgcn_s_barrier();

        // ---- phase 4: ks=1, nh=1 ; stage Bk0(t+2) ; counted vmcnt at tile end
#pragma unroll
        for (int fn = 0; fn < 2; ++fn)
            bv[fn] = rd_frag(Bcur + 16384, wn * 64 + 32 + fn * 16 + l15, l4);
        if (t + 2 < NT) stage_q(BT, K, bn, (t + 2) * 64, Bcur, tid);
        __builtin_amdgcn_s_barrier();
        asm volatile("s_waitcnt lgkmcnt(0)" ::: "memory");
        __builtin_amdgcn_s_setprio(1);
#pragma unroll
        for (int fm = 0; fm < 8; ++fm)
#pragma unroll
            for (int fn = 0; fn < 2; ++fn)
                acc[fm][2 + fn] = __builtin_amdgcn_mfma_f32_16x16x32_bf16(af[fm], bv[fn], acc[fm][2 + fn], 0, 0, 0);
        __builtin_amdgcn_s_setprio(0);
        if (t + 2 < NT) {
            asm volatile("s_waitcnt vmcnt(4)" ::: "memory");
        } else if (t + 1 < NT) {
            asm volatile("s_waitcnt vmcnt(0)" ::: "memory");
        }
        __builtin_amdgcn_s_barrier();
    }

    // ---- epilogue
    const long row_base = bm + wm * 128;
    const int col_base = (int)bn + wn * 64;
    float cs[4] = {0.f, 0.f, 0.f, 0.f}, cq[4] = {0.f, 0.f, 0.f, 0.f};
#pragma unroll
    for (int fn = 0; fn < 4; ++fn) {
        int col = col_base + fn * 16 + l15;
        float bval = bias[col];
#pragma unroll
        for (int fm = 0; fm < 8; ++fm) {
            long row0 = row_base + fm * 16 + l4 * 4;
#pragma unroll
            for (int r = 0; r < 4; ++r) {
                float v = acc[fm][fn][r] + bval;
                if (EPI == 0) {
                    v = fmaxf(v, 0.f);
                    Cb[(row0 + r) * N + col] = f2bf(v);
                } else {
                    Cf[(row0 + r) * N + col] = v;
                    cs[fn] += v;
                    cq[fn] += v * v;
                }
            }
        }
    }
    if (EPI == 1) {
#pragma unroll
        for (int fn = 0; fn < 4; ++fn) {
            float s = cs[fn], q = cq[fn];
            s += __shfl_xor(s, 16); s += __shfl_xor(s, 32);
            q += __shfl_xor(q, 16); q += __shfl_xor(q, 32);
            if (l4 == 0) {
                int col = col_base + fn * 16 + l15;
                atomicAdd(&stats[col], s);
                atomicAdd(&stats[512 + col], q);
            }
        }
    }
}

// ---------------- BN finalize
__global__ void k_zero(float* __restrict__ p) { p[threadIdx.x] = 0.f; }

__global__ void k_bnfin(const float* __restrict__ stats, const float* __restrict__ gamma,
                        const float* __restrict__ beta, float* __restrict__ ss) {
    int c = threadIdx.x;  // 512
    float mean = stats[c] * (1.f / (float)Nn);
    float var = stats[512 + c] * (1.f / (float)Nn) - mean * mean;
    float a = gamma[c] * rsqrtf(var + EPSf);
    ss[c] = a;
    ss[512 + c] = beta[c] - mean * a;
}

// ---------------- BN normalize (final layer only, no relu) -> h f32
__global__ void k_norm(const float4* __restrict__ hh4, const float* __restrict__ ss,
                       float4* __restrict__ h4) {
    const int total = Nn * 128;
    const float4* ss4 = (const float4*)ss;
    for (int idx = blockIdx.x * blockDim.x + threadIdx.x; idx < total;
         idx += gridDim.x * blockDim.x) {
        int c = idx & 127;
        float4 v = hh4[idx];
        float4 a = ss4[c], b = ss4[128 + c];
        v.x = fmaf(v.x, a.x, b.x); v.y = fmaf(v.y, a.y, b.y);
        v.z = fmaf(v.z, a.z, b.z); v.w = fmaf(v.w, a.w, b.w);
        h4[idx] = v;
    }
}

// ---------------- graph mean pool (batch is sorted)
__global__ void k_pool(const float* __restrict__ h, const int* __restrict__ batch,
                       float* __restrict__ graph) {
    int g = blockIdx.x, t = threadIdx.x;  // 512 blocks, 256 threads
    int lo = 0, hi = Nn;
    while (lo < hi) { int m = (lo + hi) >> 1; if (batch[m] < g) lo = m + 1; else hi = m; }
    int s = lo;
    lo = s; hi = Nn;
    while (lo < hi) { int m = (lo + hi) >> 1; if (batch[m] <= g) lo = m + 1; else hi = m; }
    int e = lo;
    float s0 = 0.f, s1 = 0.f;
    for (int r = s; r < e; ++r) {
        const float* row = h + (long)r * Dd;
        s0 += row[t];
        s1 += row[t + 256];
    }
    int cnt = e - s; if (cnt < 1) cnt = 1;
    float inv = 1.f / (float)cnt;
    graph[(long)g * Dd + t] = s0 * inv;
    graph[(long)g * Dd + t + 256] = s1 * inv;
}

extern "C" void kernel_launch(void* const* d_in, const int* in_sizes, int n_in,
                              void* d_out, int out_size, void* d_ws, size_t ws_size,
                              hipStream_t stream) {
    (void)in_sizes; (void)n_in; (void)out_size; (void)ws_size;
    const int* x      = (const int*)d_in[0];
    const int* ei     = (const int*)d_in[1];
    const int* ea     = (const int*)d_in[2];
    const int* batch  = (const int*)d_in[3];
    const float* xe1  = (const float*)d_in[4];
    const float* xe2  = (const float*)d_in[5];
    const float* ee1  = (const float*)d_in[6];
    const float* ee2  = (const float*)d_in[7];
    const float* W1   = (const float*)d_in[8];
    const float* b1   = (const float*)d_in[9];
    const float* W2   = (const float*)d_in[10];
    const float* b2   = (const float*)d_in[11];
    const float* gamma = (const float*)d_in[12];
    const float* beta  = (const float*)d_in[13];

    float* graph = (float*)d_out;
    float* h = graph + (size_t)Gg * Dd;  // N*D f32; aliased as hh1 bf16 [N][2D]

    char* w = (char*)d_ws;
    float* bufT = (float*)w;                    w += (size_t)Nn * Dd * 4;   // hh (GEMM2 out, f32)
    unsigned short* aggb = (unsigned short*)w;  w += (size_t)Nn * Dd * 2;   // agg bf16
    unsigned short* w1t = (unsigned short*)w;   w += (size_t)Ll * D2 * Dd * 2;
    unsigned short* w2t = (unsigned short*)w;   w += (size_t)Ll * Dd * D2 * 2;
    float* stats = (float*)w;                   w += 4096;
    float* ss = (float*)w;                      w += 4096;
    int* csr_off = (int*)w;                     w += (Nn + 1) * 4;
    int* cursor = (int*)w;                      w += Nn * 4;
    int* cnt = (int*)w;                         w += Nn * 4;
    int* csrc = (int*)w;                        w += Ee * 4;
    int* cattr = (int*)w;                       w += Ee * 4;

    // weights -> bf16 transposed [N][K]
    k_transW<<<2048, 256, 0, stream>>>(W1, w1t, Dd, D2);
    k_transW<<<2048, 256, 0, stream>>>(W2, w2t, D2, Dd);

    // atom embedding
    k_embed<<<2048, 256, 0, stream>>>(x, (const float4*)xe1, (const float4*)xe2, (float4*)h);

    // CSR build (topology constant across layers)
    k_zeroN<<<64, 1024, 0, stream>>>(cnt, Nn);
    k_hist<<<Ee / 256, 256, 0, stream>>>(ei + Ee, cnt);
    k_scan<<<1, 1024, 0, stream>>>(cnt, csr_off, cursor);
    k_place<<<Ee / 256, 256, 0, stream>>>(ei, ei + Ee, ea, cursor, csrc, cattr);

    for (int l = 0; l < Ll; ++l) {
        const float* e1l = ee1 + (size_t)l * 6 * Dd;
        const float* e2l = ee2 + (size_t)l * 3 * Dd;
        if (l == 0)
            k_gather<0><<<Nn / 4, 256, 0, stream>>>(h, nullptr, csr_off, csrc, cattr,
                                                    e1l, e2l, aggb);
        else
            k_gather<1><<<Nn / 4, 256, 0, stream>>>(bufT, ss, csr_off, csrc, cattr,
                                                    e1l, e2l, aggb);
        gemm8<0><<<(Nn / 256) * (D2 / 256), 512, 0, stream>>>(
            aggb, w1t + (size_t)l * D2 * Dd, b1 + (size_t)l * D2,
            (unsigned short*)h, nullptr, nullptr, Nn, D2, Dd);
        k_zero<<<1, 1024, 0, stream>>>(stats);
        gemm8<1><<<(Nn / 256) * (Dd / 256), 512, 0, stream>>>(
            (const unsigned short*)h, w2t + (size_t)l * Dd * D2, b2 + (size_t)l * Dd,
            nullptr, bufT, stats, Nn, Dd, D2);
        k_bnfin<<<1, 512, 0, stream>>>(stats, gamma + (size_t)l * Dd, beta + (size_t)l * Dd, ss);
    }

    // final-layer BN (no relu) -> h, then pool
    k_norm<<<2048, 256, 0, stream>>>((const float4*)bufT, ss, (float4*)h);
    k_pool<<<Gg, 256, 0, stream>>>(h, batch, graph);
}